// Round 6
// baseline (35.240 us; speedup 1.0000x reference)
//
#include <hip/hip_runtime.h>

// Problem constants (fixed by the reference's setup_inputs):
//   B=128 batches, S=32768 sequence, P=65536 path steps.
#define NB 128
#define NS 32768
#define NP 65536
#define POS_W 5.0f

constexpr int MASK_WORDS = (NB * NS) / 32;   // 131072 words = 512 KB per mask plane
constexpr int WPB        = NS / 32;          // 1024 mask words per batch (4 KB)
constexpr int LOSS_BLOCKS = 1024;

// ws layout:
//   [0, MASK_WORDS*4)                         : global targets bitmap (tbits)
//   [MASK_WORDS*4, +QPB*MASK_WORDS*4)         : QPB partial gt-mask planes
//   [after planes]                            : per-block loss partials

// ---------------------------------------------------------------------------
// One-shot: targets (16 MB int32) -> 512 KB bitmap, via per-wave ballot.
__global__ __launch_bounds__(256)
void tbit_kernel(const int* __restrict__ targets, unsigned int* __restrict__ tb) {
    constexpr int NSEG = NB * NS / 64;
    const int lane = threadIdx.x & 63;
    const int wid  = (blockIdx.x * blockDim.x + threadIdx.x) >> 6;
    const int nw   = (gridDim.x * blockDim.x) >> 6;
    for (int s = wid; s < NSEG; s += nw) {
        const unsigned long long m = __ballot(targets[(size_t)s * 64 + lane] != 0);
        if (lane == 0)       tb[s * 2]     = (unsigned int)m;
        else if (lane == 32) tb[s * 2 + 1] = (unsigned int)(m >> 32);
    }
}

// ---------------------------------------------------------------------------
// One block = (batch b, plane q). Each THREAD owns 16*SPT16 consecutive steps:
// prev-pj is register-carried (no shfl, no per-iter boundary load), and the
// 8 int4 loads per 16-step chunk are issued back-to-back (deep MLP).
// Random accesses stay in LDS; plane written with plain coalesced stores.
template <int QPB>
__global__ __launch_bounds__(512)
void gt_kernel(const int* __restrict__ pw, const unsigned int* __restrict__ tbits_g,
               unsigned int* __restrict__ pmask) {
    __shared__ unsigned int tbits[WPB];   // 4 KB: targets[b] as bits
    __shared__ unsigned int gbits[WPB];   // 4 KB: this block's gt-bit plane

    // Layout detect (uniform scalar): int64 -> hi word of last elem == 0.
    const int is64 = (pw[2 * (size_t)NP - 1] == 0);

    const int q   = blockIdx.x;
    const int b   = blockIdx.y;
    const int tid = threadIdx.x;          // 0..511

    tbits[tid]       = tbits_g[(size_t)b * WPB + tid];
    tbits[tid + 512] = tbits_g[(size_t)b * WPB + tid + 512];
    gbits[tid]       = 0u;
    gbits[tid + 512] = 0u;
    __syncthreads();

    constexpr int STEPS = NP / QPB;        // steps per block
    constexpr int SPT   = STEPS / 512;     // steps per thread (16 at QPB=8)
    const int    k0 = q * STEPS + tid * SPT;        // first step within batch
    const size_t s0 = (size_t)b * NP + (size_t)k0;  // global step index
    const int4*  p4 = (const int4*)pw;

    int prev = -1;   // sentinel: pj >= 0 always, so first step compares "new run"
    if (is64) {
        if (k0 != 0) prev = pw[4 * s0 - 2];          // pj[k0-1] lo word
        #pragma unroll
        for (int c = 0; c < SPT / 16; ++c) {
            const size_t base = s0 + (size_t)c * 16;  // one int4 per pair
            int4 a[16];
            #pragma unroll
            for (int j = 0; j < 16; ++j) a[j] = p4[base + j];
            #pragma unroll
            for (int j = 0; j < 16; ++j) {
                const int pi = a[j].x, pj = a[j].z;
                const bool f = (pj != prev);
                prev = pj;
                if (f && ((tbits[pj >> 5] >> (pj & 31)) & 1u))
                    atomicOr(&gbits[pi >> 5], 1u << (pi & 31));
            }
        }
    } else {
        if (k0 != 0) prev = pw[2 * s0 - 1];          // pj[k0-1]
        #pragma unroll
        for (int c = 0; c < SPT / 16; ++c) {
            const size_t base = (s0 >> 1) + (size_t)c * 8;  // two pairs per int4
            int4 a[8];
            #pragma unroll
            for (int j = 0; j < 8; ++j) a[j] = p4[base + j];
            #pragma unroll
            for (int j = 0; j < 8; ++j) {
                {
                    const int pi = a[j].x, pj = a[j].y;
                    const bool f = (pj != prev);
                    prev = pj;
                    if (f && ((tbits[pj >> 5] >> (pj & 31)) & 1u))
                        atomicOr(&gbits[pi >> 5], 1u << (pi & 31));
                }
                {
                    const int pi = a[j].z, pj = a[j].w;
                    const bool f = (pj != prev);
                    prev = pj;
                    if (f && ((tbits[pj >> 5] >> (pj & 31)) & 1u))
                        atomicOr(&gbits[pi >> 5], 1u << (pi & 31));
                }
            }
        }
    }
    __syncthreads();

    unsigned int* dst = pmask + (size_t)q * MASK_WORDS + (size_t)b * WPB;
    dst[tid]       = gbits[tid];
    dst[tid + 512] = gbits[tid + 512];
}

// ---------------------------------------------------------------------------
// Streaming loss, float4-vectorized; gt bit = OR of QPB partial planes
// (unrolled -> independent loads).
template <int QPB>
__global__ __launch_bounds__(256)
void loss_kernel(const float* __restrict__ preds, const unsigned int* __restrict__ pmask,
                 float* __restrict__ partials) {
    constexpr int N4 = (NB * NS) / 4;   // 1,048,576 float4s
    float acc = 0.f;
    const int stride = gridDim.x * blockDim.x;
    for (int idx = blockIdx.x * blockDim.x + threadIdx.x; idx < N4; idx += stride) {
        const float4 x = reinterpret_cast<const float4*>(preds)[idx];
        unsigned int mw = 0u;
        #pragma unroll
        for (int q = 0; q < QPB; ++q)
            mw |= pmask[(size_t)q * MASK_WORDS + (idx >> 3)];
        const unsigned int m = mw >> ((idx & 7) * 4);
        const float xs[4] = {x.x, x.y, x.z, x.w};
#pragma unroll
        for (int j = 0; j < 4; ++j) {
            const float v = xs[j];
            // stable softplus: sp(v) = log(1+exp(-|v|)) + max(v,0);  sp(-v) = sp(v) - v
            const float t = __logf(1.f + __expf(-fabsf(v)));
            const float sp_pos = t + fmaxf(v, 0.f);
            const float sp_neg = sp_pos - v;
            acc += ((m >> j) & 1u) ? POS_W * sp_neg : sp_pos;
        }
    }
    for (int off = 32; off; off >>= 1) acc += __shfl_down(acc, off);
    __shared__ float sacc[4];
    const int wave = threadIdx.x >> 6, lane = threadIdx.x & 63;
    if (lane == 0) sacc[wave] = acc;
    __syncthreads();
    if (threadIdx.x == 0) {
        float s = 0.f;
#pragma unroll
        for (int w = 0; w < 4; ++w) s += sacc[w];
        partials[blockIdx.x] = s;
    }
}

// ---------------------------------------------------------------------------
__global__ __launch_bounds__(256)
void final_kernel(const float* __restrict__ partials, float* __restrict__ out) {
    float acc = 0.f;
    for (int i = threadIdx.x; i < LOSS_BLOCKS; i += 256) acc += partials[i];
    for (int off = 32; off; off >>= 1) acc += __shfl_down(acc, off);
    __shared__ float sacc[4];
    const int wave = threadIdx.x >> 6, lane = threadIdx.x & 63;
    if (lane == 0) sacc[wave] = acc;
    __syncthreads();
    if (threadIdx.x == 0) {
        float s = 0.f;
#pragma unroll
        for (int w = 0; w < 4; ++w) s += sacc[w];
        out[0] = s * (1.0f / ((float)NB * (float)NS));
    }
}

// ---------------------------------------------------------------------------
extern "C" void kernel_launch(void* const* d_in, const int* in_sizes, int n_in,
                              void* d_out, int out_size, void* d_ws, size_t ws_size,
                              hipStream_t stream) {
    const float* preds   = (const float*)d_in[0];
    const int*   targets = (const int*)d_in[1];
    const int*   paths_w = (const int*)d_in[2];   // int32 words; layout auto-detected
    float*       out     = (float*)d_out;

    // Pick planes-per-batch by available workspace (deterministic for fixed ws).
    int qpb = 8;
    while (qpb > 1 &&
           ws_size < (size_t)(1 + qpb) * MASK_WORDS * 4 + (size_t)LOSS_BLOCKS * 4)
        qpb >>= 1;

    unsigned int* tbits_g  = (unsigned int*)d_ws;
    unsigned int* pmask    = tbits_g + MASK_WORDS;
    float*        partials = (float*)((char*)d_ws +
                              (size_t)(1 + qpb) * MASK_WORDS * 4);

    tbit_kernel<<<1024, 256, 0, stream>>>(targets, tbits_g);

    dim3 g1(qpb, NB);
    switch (qpb) {
        case 8:
            gt_kernel<8><<<g1, 512, 0, stream>>>(paths_w, tbits_g, pmask);
            loss_kernel<8><<<LOSS_BLOCKS, 256, 0, stream>>>(preds, pmask, partials);
            break;
        case 4:
            gt_kernel<4><<<g1, 512, 0, stream>>>(paths_w, tbits_g, pmask);
            loss_kernel<4><<<LOSS_BLOCKS, 256, 0, stream>>>(preds, pmask, partials);
            break;
        case 2:
            gt_kernel<2><<<g1, 512, 0, stream>>>(paths_w, tbits_g, pmask);
            loss_kernel<2><<<LOSS_BLOCKS, 256, 0, stream>>>(preds, pmask, partials);
            break;
        default:
            gt_kernel<1><<<g1, 512, 0, stream>>>(paths_w, tbits_g, pmask);
            loss_kernel<1><<<LOSS_BLOCKS, 256, 0, stream>>>(preds, pmask, partials);
            break;
    }

    final_kernel<<<1, 256, 0, stream>>>(partials, out);
}